// Round 19
// baseline (104.238 us; speedup 1.0000x reference)
//
#include <hip/hip_runtime.h>

// x_restored: (8192, 3, 20, 20) f32
// x_distorted: (8192, 5) f32
// w1: (128, 5), w2: (1200, 128), b2: (1200,)
// conv_w: (15, 6, 3, 3), conv_b: (15,)
// out: (8192, 5, 3, 20, 20) f32

#define NB 8192

typedef __attribute__((ext_vector_type(8))) short short8;
typedef __attribute__((ext_vector_type(4))) float floatx4;
typedef unsigned short u16;

__device__ inline u16 f2bf(float f) {
    unsigned int u = __float_as_uint(f);
    unsigned int r = (u + 0x7FFFu + ((u >> 16) & 1u)) >> 16;
    return (u16)r;
}
__device__ inline float bf2f(u16 u) {
    return __uint_as_float(((unsigned int)u) << 16);
}

// ------- Kernel A: h = relu(x_distorted @ w1.T) -> bf16 (B,128); + fused w2 cast -------
__global__ __launch_bounds__(256) void mlp1_kernel(const float* __restrict__ xdist,
                                                   const float* __restrict__ w1,
                                                   const float* __restrict__ w2,
                                                   u16* __restrict__ hb,
                                                   u16* __restrict__ w2b) {
    int gid = blockIdx.x * 256 + threadIdx.x;
    int b = gid >> 7, j = gid & 127;
    const float* xr = xdist + b * 5;
    const float* wr = w1 + j * 5;
    float s = xr[0] * wr[0];
    s = fmaf(xr[1], wr[1], s);
    s = fmaf(xr[2], wr[2], s);
    s = fmaf(xr[3], wr[3], s);
    s = fmaf(xr[4], wr[4], s);
    hb[gid] = f2bf(fmaxf(s, 0.0f));
    if (gid < 1200 * 128) w2b[gid] = f2bf(w2[gid]);   // fused castw2
}

// ---------------- Kernel B: xd = h @ w2.T + b2 via bf16 MFMA; OUTPUT IN BF16 ----------------
__global__ __launch_bounds__(256) void mlp2_mfma(const u16* __restrict__ hb,
                                                 const u16* __restrict__ w2b,
                                                 const float* __restrict__ b2,
                                                 u16* __restrict__ xdb) {
    const int tid = threadIdx.x;
    const int lane = tid & 63, wv = tid >> 6;
    const int tile = blockIdx.x * 4 + wv;          // 0..3199
    const int mt = tile / 25, nt = tile - mt * 25;
    const int rsel = lane & 15, kg = lane >> 4;

    short8 a[4][4], bfr[3][4];
    #pragma unroll
    for (int mi = 0; mi < 4; ++mi) {
        const u16* ap = hb + (size_t)(mt * 64 + mi * 16 + rsel) * 128 + kg * 8;
        #pragma unroll
        for (int ks = 0; ks < 4; ++ks) a[mi][ks] = *(const short8*)(ap + ks * 32);
    }
    #pragma unroll
    for (int ni = 0; ni < 3; ++ni) {
        const u16* bp = w2b + (size_t)(nt * 48 + ni * 16 + rsel) * 128 + kg * 8;
        #pragma unroll
        for (int ks = 0; ks < 4; ++ks) bfr[ni][ks] = *(const short8*)(bp + ks * 32);
    }
    floatx4 acc[4][3];
    #pragma unroll
    for (int mi = 0; mi < 4; ++mi)
        #pragma unroll
        for (int ni = 0; ni < 3; ++ni)
            acc[mi][ni] = (floatx4){0.f, 0.f, 0.f, 0.f};

    #pragma unroll
    for (int ks = 0; ks < 4; ++ks)
        #pragma unroll
        for (int mi = 0; mi < 4; ++mi)
            #pragma unroll
            for (int ni = 0; ni < 3; ++ni)
                acc[mi][ni] = __builtin_amdgcn_mfma_f32_16x16x32_bf16(
                    a[mi][ks], bfr[ni][ks], acc[mi][ni], 0, 0, 0);

    #pragma unroll
    for (int ni = 0; ni < 3; ++ni) {
        float bias = b2[nt * 48 + ni * 16 + rsel];
        #pragma unroll
        for (int mi = 0; mi < 4; ++mi) {
            #pragma unroll
            for (int r = 0; r < 4; ++r) {
                int m = mt * 64 + mi * 16 + kg * 4 + r;
                xdb[(size_t)m * 1200 + nt * 48 + ni * 16 + rsel] = f2bf(acc[mi][ni][r] + bias);
            }
        }
    }
}

#define XS2 24            // xpad row stride (u16, EVEN: left pad 2 -> dword-aligned fill)
#define XPL 528           // xpad plane stride (u16) = 22*24
#define XPLD 264          // xpad plane stride (dwords)
#define WLS 424           // wl row stride (u16); dword stride 212; K padded to 416

// ---------------- Kernel C: conv via MFMA + per-wave gram-MFMA + GS, 256 thr/sample -----
// R18 + float2-ized combine: 200 threads x 2 consecutive px -> each wl read is ONE
// ds_read_b32 (2 bf16), each store a dwordx2; combine critical path halves (60->30 ops).
__global__ __launch_bounds__(256) void conv_gs_kernel(const u16* __restrict__ xdb,
                                                      const float* __restrict__ xres,
                                                      const float* __restrict__ cw,
                                                      const float* __restrict__ cb,
                                                      float* __restrict__ out) {
    const int b = blockIdx.x;
    const int tid = threadIdx.x;  // 0..255
    const int lane = tid & 63, wv = tid >> 6;
    const int rsel = lane & 15, kg = lane >> 4;
    __shared__ __align__(16) u16 xpad[6 * XPL];    // 3168 u16; aliased as Gsh after conv
    __shared__ __align__(16) u16 wl16[16 * WLS];   // conv output bf16 [oc][px]

    // ---- per-thread setup (no LDS deps) ----
    short8 bf0, bf1;
    #pragma unroll
    for (int j = 0; j < 8; ++j) {
        int k0 = kg * 8 + j;
        int k1 = 32 + kg * 8 + j;
        float v0 = (rsel < 15 && k0 < 54) ? cw[rsel * 54 + k0] : 0.f;
        float v1 = (rsel < 15 && k1 < 54) ? cw[rsel * 54 + k1] : 0.f;
        bf0[j] = (short)f2bf(v0);
        bf1[j] = (short)f2bf(v1);
    }
    const float bias = cb[rsel < 15 ? rsel : 14];
    int offA[16];
    #pragma unroll
    for (int q = 0; q < 16; ++q) {
        int k = (q >> 3) * 32 + kg * 8 + (q & 7);
        int ci = k / 9, tap = k - ci * 9, dy = tap / 3, dx = tap - dy * 3;
        offA[q] = (k < 54) ? (ci * XPL + dy * XS2 + dx) : 0;
    }

    unsigned int* xz = (unsigned int*)xpad;
    // ---- border-only zero (dword rows 0/21 + col22-23; u16 col 1) + wl K-pad ----
    #pragma unroll
    for (int i2 = 0; i2 < 2; ++i2) {
        int i = tid + i2 * 256;
        if (i < 264) {
            int pl = i / 44, d = i - pl * 44;
            int dw;
            if (d < 12) dw = d;                      // row 0
            else if (d < 24) dw = 252 + (d - 12);    // row 21
            else dw = (d - 23) * 12 + 11;            // cols 22-23, rows 1..20
            xz[pl * XPLD + dw] = 0u;
        }
    }
    if (tid < 120) {
        int pl = tid / 20, r = tid % 20 + 1;
        xpad[pl * XPL + r * 24 + 1] = 0;             // col 1, rows 1..20
    }
    if (tid < 180) {
        int row = tid / 12, d = tid % 12;
        ((unsigned int*)wl16)[row * 212 + 200 + d] = 0u;  // wl K-pad (u16 400..423)
    }

    // ---- vectorized interior fill (disjoint from border -> no barrier needed) ----
    const unsigned int* s0d = (const unsigned int*)(xdb + (size_t)b * 1200);
    const float2* s1d = (const float2*)(xres + (size_t)b * 1200);
    #pragma unroll
    for (int i2 = 0; i2 < 3; ++i2) {
        int i = tid + i2 * 256;
        if (i < 600) {
            int c = i / 200, rem = i - c * 200;
            int p = rem * 2, y = p / 20, x = p - (p / 20) * 20;   // x even
            xz[c * XPLD + (y + 1) * 12 + (x + 2) / 2] = s0d[i];
        }
    }
    #pragma unroll
    for (int i2 = 0; i2 < 3; ++i2) {
        int i = tid + i2 * 256;
        if (i < 600) {
            int c = i / 200, rem = i - c * 200;
            int p = rem * 2, y = p / 20, x = p - (p / 20) * 20;
            float2 v = s1d[i];
            unsigned int pk;
            asm volatile("v_cvt_pk_bf16_f32 %0, %1, %2" : "=v"(pk) : "v"(v.x), "v"(v.y));
            xz[(3 + c) * XPLD + (y + 1) * 12 + (x + 2) / 2] = pk;
        }
    }
    __syncthreads();   // barrier 1: xpad ready

    // ---- conv via MFMA: wave wv handles tiles t = wv, wv+4, ... < 25 ----
    for (int t = wv; t < 25; t += 4) {
        const int px = t * 16 + rsel;
        const int y = px / 20;
        const int pb = y * XS2 + (px - y * 20) + 1;   // window top-left (col = x+1)
        short8 a0, a1;
        #pragma unroll
        for (int j = 0; j < 8; ++j) a0[j] = (short)xpad[pb + offA[j]];
        #pragma unroll
        for (int j = 0; j < 8; ++j) a1[j] = (short)xpad[pb + offA[8 + j]];
        floatx4 acc = (floatx4){bias, bias, bias, bias};
        acc = __builtin_amdgcn_mfma_f32_16x16x32_bf16(a0, bf0, acc, 0, 0, 0);
        acc = __builtin_amdgcn_mfma_f32_16x16x32_bf16(a1, bf1, acc, 0, 0, 0);
        if (rsel < 15) {
            unsigned int lo, hi;
            asm volatile("v_cvt_pk_bf16_f32 %0, %1, %2" : "=v"(lo) : "v"(acc[0]), "v"(acc[1]));
            asm volatile("v_cvt_pk_bf16_f32 %0, %1, %2" : "=v"(hi) : "v"(acc[2]), "v"(acc[3]));
            *(uint2*)(wl16 + rsel * WLS + t * 16 + kg * 4) = make_uint2(lo, hi);
        }
    }
    __syncthreads();   // barrier 2: wl ready (xpad now dead -> reuse as Gsh)

    // ---- channel-Gram via MFMA, PER WAVE (no wave idles, no trailing barrier) ----
    float* Gw = ((float*)xpad) + wv * 272;   // 16x17 floats per wave
    {
        floatx4 gacc = (floatx4){0.f, 0.f, 0.f, 0.f};
        #pragma unroll
        for (int s = 0; s < 13; ++s) {
            short8 f = *(const short8*)(wl16 + rsel * WLS + s * 32 + kg * 8);
            gacc = __builtin_amdgcn_mfma_f32_16x16x32_bf16(f, f, gacc, 0, 0, 0);
        }
        #pragma unroll
        for (int r = 0; r < 4; ++r)
            Gw[(kg * 4 + r) * 17 + rsel] = gacc[r];
    }
    // same-wave lgkm ordering guarantees visibility of Gw writes to these reads
    float Gd[5][5];
    #pragma unroll
    for (int d = 0; d < 5; ++d)
        #pragma unroll
        for (int e = 0; e < 5; ++e)
            Gd[d][e] = Gw[(3 * d) * 17 + 3 * e] +
                       Gw[(3 * d + 1) * 17 + 3 * e + 1] +
                       Gw[(3 * d + 2) * 17 + 3 * e + 2];

    // ---- per-thread Gram-space modified GS solve ----
    float A[5][5];
    #pragma unroll
    for (int i = 0; i < 5; ++i)
        #pragma unroll
        for (int j = 0; j < 5; ++j) A[i][j] = (i == j) ? 1.f : 0.f;
    #pragma unroll
    for (int j = 0; j < 4; ++j) {
        float v[5];
        #pragma unroll
        for (int rr = 0; rr < 5; ++rr) {
            float s0a = 0.f;
            #pragma unroll
            for (int k = 0; k < 5; ++k)
                if (k <= j) s0a = fmaf(A[j][k], Gd[k][rr], s0a);
            v[rr] = s0a;
        }
        float dj = 0.f;
        #pragma unroll
        for (int k = 0; k < 5; ++k)
            if (k <= j) dj = fmaf(A[j][k], v[k], dj);
        float rd = 1.0f / dj;
        #pragma unroll
        for (int i = j + 1; i < 5; ++i) {
            float cij = 0.f;
            #pragma unroll
            for (int k = 0; k < 5; ++k)
                if (k <= i) cij = fmaf(A[i][k], v[k], cij);
            cij *= rd;
            #pragma unroll
            for (int k = 0; k < 5; ++k)
                if (k <= j) A[i][k] = fmaf(-cij, A[j][k], A[i][k]);
        }
    }
    float a10[10];
    a10[0] = A[1][0];
    a10[1] = A[2][0]; a10[2] = A[2][1];
    a10[3] = A[3][0]; a10[4] = A[3][1]; a10[5] = A[3][2];
    a10[6] = A[4][0]; a10[7] = A[4][1]; a10[8] = A[4][2]; a10[9] = A[4][3];

    // ---- combine + store: 200 threads x 2 px; b32 wl reads, dwordx2 stores ----
    if (tid < 200) {
        const unsigned int* wld = (const unsigned int*)wl16;
        float* ob = out + (size_t)b * 6000 + 2 * tid;
        #pragma unroll
        for (int cc = 0; cc < 3; ++cc) {
            unsigned int r0 = wld[(0 + cc) * 212 + tid];
            unsigned int r1 = wld[(3 + cc) * 212 + tid];
            unsigned int r2 = wld[(6 + cc) * 212 + tid];
            unsigned int r3 = wld[(9 + cc) * 212 + tid];
            unsigned int r4 = wld[(12 + cc) * 212 + tid];
            float w0a = __uint_as_float(r0 << 16), w0b = __uint_as_float(r0 & 0xffff0000u);
            float w1a = __uint_as_float(r1 << 16), w1b = __uint_as_float(r1 & 0xffff0000u);
            float w2a = __uint_as_float(r2 << 16), w2b_ = __uint_as_float(r2 & 0xffff0000u);
            float w3a = __uint_as_float(r3 << 16), w3b = __uint_as_float(r3 & 0xffff0000u);
            float w4a = __uint_as_float(r4 << 16), w4b = __uint_as_float(r4 & 0xffff0000u);
            float2 o0 = make_float2(w0a, w0b);
            float2 o1 = make_float2(fmaf(a10[0], w0a, w1a),
                                    fmaf(a10[0], w0b, w1b));
            float2 o2 = make_float2(fmaf(a10[2], w1a, fmaf(a10[1], w0a, w2a)),
                                    fmaf(a10[2], w1b, fmaf(a10[1], w0b, w2b_)));
            float2 o3 = make_float2(
                fmaf(a10[5], w2a, fmaf(a10[4], w1a, fmaf(a10[3], w0a, w3a))),
                fmaf(a10[5], w2b_, fmaf(a10[4], w1b, fmaf(a10[3], w0b, w3b))));
            float2 o4 = make_float2(
                fmaf(a10[9], w3a, fmaf(a10[8], w2a, fmaf(a10[7], w1a, fmaf(a10[6], w0a, w4a)))),
                fmaf(a10[9], w3b, fmaf(a10[8], w2b_, fmaf(a10[7], w1b, fmaf(a10[6], w0b, w4b)))));
            *(float2*)(ob + (0 + cc) * 400) = o0;
            *(float2*)(ob + (3 + cc) * 400) = o1;
            *(float2*)(ob + (6 + cc) * 400) = o2;
            *(float2*)(ob + (9 + cc) * 400) = o3;
            *(float2*)(ob + (12 + cc) * 400) = o4;
        }
    }
}

extern "C" void kernel_launch(void* const* d_in, const int* in_sizes, int n_in,
                              void* d_out, int out_size, void* d_ws, size_t ws_size,
                              hipStream_t stream) {
    const float* x_restored  = (const float*)d_in[0];
    const float* x_distorted = (const float*)d_in[1];
    const float* w1          = (const float*)d_in[2];
    const float* w2          = (const float*)d_in[3];
    const float* b2          = (const float*)d_in[4];
    const float* conv_w      = (const float*)d_in[5];
    const float* conv_b      = (const float*)d_in[6];
    float* out = (float*)d_out;

    u16* xdb = (u16*)d_ws;                           // 8192*1200 bf16 = 19.7 MB
    u16* hb  = xdb + (size_t)NB * 1200;              // 8192*128 bf16 = 2 MB
    u16* w2b = hb + (size_t)NB * 128;                // 1200*128 bf16 = 0.3 MB

    mlp1_kernel<<<(NB * 128) / 256, 256, 0, stream>>>(x_distorted, w1, w2, hb, w2b);
    mlp2_mfma<<<(128 * 25) / 4, 256, 0, stream>>>(hb, w2b, b2, xdb);
    conv_gs_kernel<<<NB, 256, 0, stream>>>(xdb, x_restored, conv_w, conv_b, out);
}

// Round 20
// 95.923 us; speedup vs baseline: 1.0867x; 1.0867x over previous
//
#include <hip/hip_runtime.h>

// x_restored: (8192, 3, 20, 20) f32
// x_distorted: (8192, 5) f32
// w1: (128, 5), w2: (1200, 128), b2: (1200,)
// conv_w: (15, 6, 3, 3), conv_b: (15,)
// out: (8192, 5, 3, 20, 20) f32

#define NB 8192

typedef __attribute__((ext_vector_type(8))) short short8;
typedef __attribute__((ext_vector_type(4))) float floatx4;
typedef unsigned short u16;

__device__ inline u16 f2bf(float f) {
    unsigned int u = __float_as_uint(f);
    unsigned int r = (u + 0x7FFFu + ((u >> 16) & 1u)) >> 16;
    return (u16)r;
}
__device__ inline float bf2f(u16 u) {
    return __uint_as_float(((unsigned int)u) << 16);
}

// ------- Kernel A: h = relu(x_distorted @ w1.T) -> bf16 (B,128); + fused w2 cast -------
// Cast guard is BLOCK-uniform: 600*256 == 1200*128 == 153600 exactly.
__global__ __launch_bounds__(256) void mlp1_kernel(const float* __restrict__ xdist,
                                                   const float* __restrict__ w1,
                                                   const float* __restrict__ w2,
                                                   u16* __restrict__ hb,
                                                   u16* __restrict__ w2b) {
    int gid = blockIdx.x * 256 + threadIdx.x;
    int b = gid >> 7, j = gid & 127;
    const float* xr = xdist + b * 5;
    const float* wr = w1 + j * 5;
    float s = xr[0] * wr[0];
    s = fmaf(xr[1], wr[1], s);
    s = fmaf(xr[2], wr[2], s);
    s = fmaf(xr[3], wr[3], s);
    s = fmaf(xr[4], wr[4], s);
    hb[gid] = f2bf(fmaxf(s, 0.0f));
    if (blockIdx.x < 600) w2b[gid] = f2bf(w2[gid]);   // fused castw2 (uniform branch)
}

// ---------------- Kernel B: xd = h @ w2.T + b2 via bf16 MFMA; OUTPUT IN BF16 ----------------
__global__ __launch_bounds__(256) void mlp2_mfma(const u16* __restrict__ hb,
                                                 const u16* __restrict__ w2b,
                                                 const float* __restrict__ b2,
                                                 u16* __restrict__ xdb) {
    const int tid = threadIdx.x;
    const int lane = tid & 63, wv = tid >> 6;
    const int tile = blockIdx.x * 4 + wv;          // 0..3199
    const int mt = tile / 25, nt = tile - mt * 25;
    const int rsel = lane & 15, kg = lane >> 4;

    short8 a[4][4], bfr[3][4];
    #pragma unroll
    for (int mi = 0; mi < 4; ++mi) {
        const u16* ap = hb + (size_t)(mt * 64 + mi * 16 + rsel) * 128 + kg * 8;
        #pragma unroll
        for (int ks = 0; ks < 4; ++ks) a[mi][ks] = *(const short8*)(ap + ks * 32);
    }
    #pragma unroll
    for (int ni = 0; ni < 3; ++ni) {
        const u16* bp = w2b + (size_t)(nt * 48 + ni * 16 + rsel) * 128 + kg * 8;
        #pragma unroll
        for (int ks = 0; ks < 4; ++ks) bfr[ni][ks] = *(const short8*)(bp + ks * 32);
    }
    floatx4 acc[4][3];
    #pragma unroll
    for (int mi = 0; mi < 4; ++mi)
        #pragma unroll
        for (int ni = 0; ni < 3; ++ni)
            acc[mi][ni] = (floatx4){0.f, 0.f, 0.f, 0.f};

    #pragma unroll
    for (int ks = 0; ks < 4; ++ks)
        #pragma unroll
        for (int mi = 0; mi < 4; ++mi)
            #pragma unroll
            for (int ni = 0; ni < 3; ++ni)
                acc[mi][ni] = __builtin_amdgcn_mfma_f32_16x16x32_bf16(
                    a[mi][ks], bfr[ni][ks], acc[mi][ni], 0, 0, 0);

    #pragma unroll
    for (int ni = 0; ni < 3; ++ni) {
        float bias = b2[nt * 48 + ni * 16 + rsel];
        #pragma unroll
        for (int mi = 0; mi < 4; ++mi) {
            #pragma unroll
            for (int r = 0; r < 4; ++r) {
                int m = mt * 64 + mi * 16 + kg * 4 + r;
                xdb[(size_t)m * 1200 + nt * 48 + ni * 16 + rsel] = f2bf(acc[mi][ni][r] + bias);
            }
        }
    }
}

#define XS2 24            // xpad row stride (u16, EVEN: left pad 2 -> dword-aligned fill)
#define XPL 528           // xpad plane stride (u16) = 22*24
#define XPLD 264          // xpad plane stride (dwords)
#define WLS 424           // wl row stride (u16); K padded to 416 for gram MFMA

// ---------------- Kernel C: conv via MFMA + per-wave gram-MFMA + GS, 256 thr/sample -----
// EXACT R18 kernel (verified 92.2 us): 2 barriers, border-only zero, vectorized fill,
// per-wave gram-MFMA aliased onto dead xpad, per-thread solve, two-pass scalar combine.
__global__ __launch_bounds__(256) void conv_gs_kernel(const u16* __restrict__ xdb,
                                                      const float* __restrict__ xres,
                                                      const float* __restrict__ cw,
                                                      const float* __restrict__ cb,
                                                      float* __restrict__ out) {
    const int b = blockIdx.x;
    const int tid = threadIdx.x;  // 0..255
    const int lane = tid & 63, wv = tid >> 6;
    const int rsel = lane & 15, kg = lane >> 4;
    __shared__ __align__(16) u16 xpad[6 * XPL];    // 3168 u16; aliased as Gsh after conv
    __shared__ __align__(16) u16 wl16[16 * WLS];   // conv output bf16 [oc][px]

    // ---- per-thread setup (no LDS deps) ----
    short8 bf0, bf1;
    #pragma unroll
    for (int j = 0; j < 8; ++j) {
        int k0 = kg * 8 + j;
        int k1 = 32 + kg * 8 + j;
        float v0 = (rsel < 15 && k0 < 54) ? cw[rsel * 54 + k0] : 0.f;
        float v1 = (rsel < 15 && k1 < 54) ? cw[rsel * 54 + k1] : 0.f;
        bf0[j] = (short)f2bf(v0);
        bf1[j] = (short)f2bf(v1);
    }
    const float bias = cb[rsel < 15 ? rsel : 14];
    int offA[16];
    #pragma unroll
    for (int q = 0; q < 16; ++q) {
        int k = (q >> 3) * 32 + kg * 8 + (q & 7);
        int ci = k / 9, tap = k - ci * 9, dy = tap / 3, dx = tap - dy * 3;
        offA[q] = (k < 54) ? (ci * XPL + dy * XS2 + dx) : 0;
    }

    unsigned int* xz = (unsigned int*)xpad;
    // ---- border-only zero (dword rows 0/21 + col22-23; u16 col 1) + wl K-pad ----
    #pragma unroll
    for (int i2 = 0; i2 < 2; ++i2) {
        int i = tid + i2 * 256;
        if (i < 264) {
            int pl = i / 44, d = i - pl * 44;
            int dw;
            if (d < 12) dw = d;                      // row 0
            else if (d < 24) dw = 252 + (d - 12);    // row 21
            else dw = (d - 23) * 12 + 11;            // cols 22-23, rows 1..20
            xz[pl * XPLD + dw] = 0u;
        }
    }
    if (tid < 120) {
        int pl = tid / 20, r = tid % 20 + 1;
        xpad[pl * XPL + r * 24 + 1] = 0;             // col 1, rows 1..20
    }
    if (tid < 180) {
        int row = tid / 12, d = tid % 12;
        ((unsigned int*)wl16)[row * 212 + 200 + d] = 0u;  // wl K-pad (u16 400..423)
    }

    // ---- vectorized interior fill (disjoint from border -> no barrier needed) ----
    const unsigned int* s0d = (const unsigned int*)(xdb + (size_t)b * 1200);
    const float2* s1d = (const float2*)(xres + (size_t)b * 1200);
    #pragma unroll
    for (int i2 = 0; i2 < 3; ++i2) {
        int i = tid + i2 * 256;
        if (i < 600) {
            int c = i / 200, rem = i - c * 200;
            int p = rem * 2, y = p / 20, x = p - (p / 20) * 20;   // x even
            xz[c * XPLD + (y + 1) * 12 + (x + 2) / 2] = s0d[i];
        }
    }
    #pragma unroll
    for (int i2 = 0; i2 < 3; ++i2) {
        int i = tid + i2 * 256;
        if (i < 600) {
            int c = i / 200, rem = i - c * 200;
            int p = rem * 2, y = p / 20, x = p - (p / 20) * 20;
            float2 v = s1d[i];
            unsigned int pk;
            asm volatile("v_cvt_pk_bf16_f32 %0, %1, %2" : "=v"(pk) : "v"(v.x), "v"(v.y));
            xz[(3 + c) * XPLD + (y + 1) * 12 + (x + 2) / 2] = pk;
        }
    }
    __syncthreads();   // barrier 1: xpad ready

    // ---- conv via MFMA: wave wv handles tiles t = wv, wv+4, ... < 25 ----
    for (int t = wv; t < 25; t += 4) {
        const int px = t * 16 + rsel;
        const int y = px / 20;
        const int pb = y * XS2 + (px - y * 20) + 1;   // window top-left (col = x+1)
        short8 a0, a1;
        #pragma unroll
        for (int j = 0; j < 8; ++j) a0[j] = (short)xpad[pb + offA[j]];
        #pragma unroll
        for (int j = 0; j < 8; ++j) a1[j] = (short)xpad[pb + offA[8 + j]];
        floatx4 acc = (floatx4){bias, bias, bias, bias};
        acc = __builtin_amdgcn_mfma_f32_16x16x32_bf16(a0, bf0, acc, 0, 0, 0);
        acc = __builtin_amdgcn_mfma_f32_16x16x32_bf16(a1, bf1, acc, 0, 0, 0);
        if (rsel < 15) {
            unsigned int lo, hi;
            asm volatile("v_cvt_pk_bf16_f32 %0, %1, %2" : "=v"(lo) : "v"(acc[0]), "v"(acc[1]));
            asm volatile("v_cvt_pk_bf16_f32 %0, %1, %2" : "=v"(hi) : "v"(acc[2]), "v"(acc[3]));
            *(uint2*)(wl16 + rsel * WLS + t * 16 + kg * 4) = make_uint2(lo, hi);
        }
    }
    __syncthreads();   // barrier 2: wl ready (xpad now dead -> reuse as Gsh)

    // ---- channel-Gram via MFMA, PER WAVE (no wave idles, no trailing barrier) ----
    float* Gw = ((float*)xpad) + wv * 272;   // 16x17 floats per wave
    {
        floatx4 gacc = (floatx4){0.f, 0.f, 0.f, 0.f};
        #pragma unroll
        for (int s = 0; s < 13; ++s) {
            short8 f = *(const short8*)(wl16 + rsel * WLS + s * 32 + kg * 8);
            gacc = __builtin_amdgcn_mfma_f32_16x16x32_bf16(f, f, gacc, 0, 0, 0);
        }
        #pragma unroll
        for (int r = 0; r < 4; ++r)
            Gw[(kg * 4 + r) * 17 + rsel] = gacc[r];
    }
    // same-wave lgkm ordering guarantees visibility of Gw writes to these reads
    float Gd[5][5];
    #pragma unroll
    for (int d = 0; d < 5; ++d)
        #pragma unroll
        for (int e = 0; e < 5; ++e)
            Gd[d][e] = Gw[(3 * d) * 17 + 3 * e] +
                       Gw[(3 * d + 1) * 17 + 3 * e + 1] +
                       Gw[(3 * d + 2) * 17 + 3 * e + 2];

    // ---- per-thread Gram-space modified GS solve ----
    float A[5][5];
    #pragma unroll
    for (int i = 0; i < 5; ++i)
        #pragma unroll
        for (int j = 0; j < 5; ++j) A[i][j] = (i == j) ? 1.f : 0.f;
    #pragma unroll
    for (int j = 0; j < 4; ++j) {
        float v[5];
        #pragma unroll
        for (int rr = 0; rr < 5; ++rr) {
            float s0a = 0.f;
            #pragma unroll
            for (int k = 0; k < 5; ++k)
                if (k <= j) s0a = fmaf(A[j][k], Gd[k][rr], s0a);
            v[rr] = s0a;
        }
        float dj = 0.f;
        #pragma unroll
        for (int k = 0; k < 5; ++k)
            if (k <= j) dj = fmaf(A[j][k], v[k], dj);
        float rd = 1.0f / dj;
        #pragma unroll
        for (int i = j + 1; i < 5; ++i) {
            float cij = 0.f;
            #pragma unroll
            for (int k = 0; k < 5; ++k)
                if (k <= i) cij = fmaf(A[i][k], v[k], cij);
            cij *= rd;
            #pragma unroll
            for (int k = 0; k < 5; ++k)
                if (k <= j) A[i][k] = fmaf(-cij, A[j][k], A[i][k]);
        }
    }
    float a10[10];
    a10[0] = A[1][0];
    a10[1] = A[2][0]; a10[2] = A[2][1];
    a10[3] = A[3][0]; a10[4] = A[3][1]; a10[5] = A[3][2];
    a10[6] = A[4][0]; a10[7] = A[4][1]; a10[8] = A[4][2]; a10[9] = A[4][3];

    // ---- combine + store: 256 + 144 positions, coalesced scalar stores ----
    float* ob = out + (size_t)b * 6000;
    #pragma unroll
    for (int pp = 0; pp < 2; ++pp) {
        if (pp == 0 || tid < 144) {
            const int pos = tid + pp * 256;
            #pragma unroll
            for (int cc = 0; cc < 3; ++cc) {
                float w0 = bf2f(wl16[(0 + cc) * WLS + pos]);
                float w1 = bf2f(wl16[(3 + cc) * WLS + pos]);
                float w2v = bf2f(wl16[(6 + cc) * WLS + pos]);
                float w3 = bf2f(wl16[(9 + cc) * WLS + pos]);
                float w4 = bf2f(wl16[(12 + cc) * WLS + pos]);
                float u4 = fmaf(a10[9], w3, fmaf(a10[8], w2v, fmaf(a10[7], w1, fmaf(a10[6], w0, w4))));
                float u3 = fmaf(a10[5], w2v, fmaf(a10[4], w1, fmaf(a10[3], w0, w3)));
                float u2 = fmaf(a10[2], w1, fmaf(a10[1], w0, w2v));
                float u1 = fmaf(a10[0], w0, w1);
                ob[(0 + cc) * 400 + pos] = w0;
                ob[(3 + cc) * 400 + pos] = u1;
                ob[(6 + cc) * 400 + pos] = u2;
                ob[(9 + cc) * 400 + pos] = u3;
                ob[(12 + cc) * 400 + pos] = u4;
            }
        }
    }
}

extern "C" void kernel_launch(void* const* d_in, const int* in_sizes, int n_in,
                              void* d_out, int out_size, void* d_ws, size_t ws_size,
                              hipStream_t stream) {
    const float* x_restored  = (const float*)d_in[0];
    const float* x_distorted = (const float*)d_in[1];
    const float* w1          = (const float*)d_in[2];
    const float* w2          = (const float*)d_in[3];
    const float* b2          = (const float*)d_in[4];
    const float* conv_w      = (const float*)d_in[5];
    const float* conv_b      = (const float*)d_in[6];
    float* out = (float*)d_out;

    u16* xdb = (u16*)d_ws;                           // 8192*1200 bf16 = 19.7 MB
    u16* hb  = xdb + (size_t)NB * 1200;              // 8192*128 bf16 = 2 MB
    u16* w2b = hb + (size_t)NB * 128;                // 1200*128 bf16 = 0.3 MB

    mlp1_kernel<<<(NB * 128) / 256, 256, 0, stream>>>(x_distorted, w1, w2, hb, w2b);
    mlp2_mfma<<<(128 * 25) / 4, 256, 0, stream>>>(hb, w2b, b2, xdb);
    conv_gs_kernel<<<NB, 256, 0, stream>>>(xdb, x_restored, conv_w, conv_b, out);
}

// Round 21
// 94.262 us; speedup vs baseline: 1.1058x; 1.0176x over previous
//
#include <hip/hip_runtime.h>

// x_restored: (8192, 3, 20, 20) f32
// x_distorted: (8192, 5) f32
// w1: (128, 5), w2: (1200, 128), b2: (1200,)
// conv_w: (15, 6, 3, 3), conv_b: (15,)
// out: (8192, 5, 3, 20, 20) f32

#define NB 8192

typedef __attribute__((ext_vector_type(8))) short short8;
typedef __attribute__((ext_vector_type(4))) float floatx4;
typedef unsigned short u16;

__device__ inline u16 f2bf(float f) {
    unsigned int u = __float_as_uint(f);
    unsigned int r = (u + 0x7FFFu + ((u >> 16) & 1u)) >> 16;
    return (u16)r;
}
__device__ inline float bf2f(u16 u) {
    return __uint_as_float(((unsigned int)u) << 16);
}

// ---------------- Kernel A: h = relu(x_distorted @ w1.T) -> bf16, (B,128) ----------------
__global__ __launch_bounds__(256) void mlp1_kernel(const float* __restrict__ xdist,
                                                   const float* __restrict__ w1,
                                                   u16* __restrict__ hb) {
    int gid = blockIdx.x * 256 + threadIdx.x;
    int b = gid >> 7, j = gid & 127;
    const float* xr = xdist + b * 5;
    const float* wr = w1 + j * 5;
    float s = xr[0] * wr[0];
    s = fmaf(xr[1], wr[1], s);
    s = fmaf(xr[2], wr[2], s);
    s = fmaf(xr[3], wr[3], s);
    s = fmaf(xr[4], wr[4], s);
    hb[gid] = f2bf(fmaxf(s, 0.0f));
}

// ---------------- cast w2 -> bf16 ----------------
__global__ __launch_bounds__(256) void castw2_kernel(const float* __restrict__ w2,
                                                     u16* __restrict__ w2b) {
    int i = blockIdx.x * 256 + threadIdx.x;   // 1200*128 = 153600 exactly
    w2b[i] = f2bf(w2[i]);
}

// ---------------- Kernel B: xd = h @ w2.T + b2 via bf16 MFMA; OUTPUT IN BF16 ----------------
__global__ __launch_bounds__(256) void mlp2_mfma(const u16* __restrict__ hb,
                                                 const u16* __restrict__ w2b,
                                                 const float* __restrict__ b2,
                                                 u16* __restrict__ xdb) {
    const int tid = threadIdx.x;
    const int lane = tid & 63, wv = tid >> 6;
    const int tile = blockIdx.x * 4 + wv;          // 0..3199
    const int mt = tile / 25, nt = tile - mt * 25;
    const int rsel = lane & 15, kg = lane >> 4;

    short8 a[4][4], bfr[3][4];
    #pragma unroll
    for (int mi = 0; mi < 4; ++mi) {
        const u16* ap = hb + (size_t)(mt * 64 + mi * 16 + rsel) * 128 + kg * 8;
        #pragma unroll
        for (int ks = 0; ks < 4; ++ks) a[mi][ks] = *(const short8*)(ap + ks * 32);
    }
    #pragma unroll
    for (int ni = 0; ni < 3; ++ni) {
        const u16* bp = w2b + (size_t)(nt * 48 + ni * 16 + rsel) * 128 + kg * 8;
        #pragma unroll
        for (int ks = 0; ks < 4; ++ks) bfr[ni][ks] = *(const short8*)(bp + ks * 32);
    }
    floatx4 acc[4][3];
    #pragma unroll
    for (int mi = 0; mi < 4; ++mi)
        #pragma unroll
        for (int ni = 0; ni < 3; ++ni)
            acc[mi][ni] = (floatx4){0.f, 0.f, 0.f, 0.f};

    #pragma unroll
    for (int ks = 0; ks < 4; ++ks)
        #pragma unroll
        for (int mi = 0; mi < 4; ++mi)
            #pragma unroll
            for (int ni = 0; ni < 3; ++ni)
                acc[mi][ni] = __builtin_amdgcn_mfma_f32_16x16x32_bf16(
                    a[mi][ks], bfr[ni][ks], acc[mi][ni], 0, 0, 0);

    #pragma unroll
    for (int ni = 0; ni < 3; ++ni) {
        float bias = b2[nt * 48 + ni * 16 + rsel];
        #pragma unroll
        for (int mi = 0; mi < 4; ++mi) {
            #pragma unroll
            for (int r = 0; r < 4; ++r) {
                int m = mt * 64 + mi * 16 + kg * 4 + r;
                xdb[(size_t)m * 1200 + nt * 48 + ni * 16 + rsel] = f2bf(acc[mi][ni][r] + bias);
            }
        }
    }
}

#define XS2 24            // xpad row stride (u16, EVEN: left pad 2 -> dword-aligned fill)
#define XPL 528           // xpad plane stride (u16) = 22*24
#define XPLD 264          // xpad plane stride (dwords)
#define WLS 424           // wl row stride (u16); K padded to 416 for gram MFMA

// ---------------- Kernel C: conv via MFMA + per-wave gram-MFMA + GS, 256 thr/sample -----
// EXACT R18 kernel except: Gd fold uses SYMMETRY (45 broadcast LDS reads instead of 75;
// lower triangle mirrored in registers). conv_gs is LDS-issue-slot bound (~250 slots/thr
// x 32 waves/CU x ~5.8cyc ~= observed time), so cutting slots is the lever.
__global__ __launch_bounds__(256) void conv_gs_kernel(const u16* __restrict__ xdb,
                                                      const float* __restrict__ xres,
                                                      const float* __restrict__ cw,
                                                      const float* __restrict__ cb,
                                                      float* __restrict__ out) {
    const int b = blockIdx.x;
    const int tid = threadIdx.x;  // 0..255
    const int lane = tid & 63, wv = tid >> 6;
    const int rsel = lane & 15, kg = lane >> 4;
    __shared__ __align__(16) u16 xpad[6 * XPL];    // 3168 u16; aliased as Gsh after conv
    __shared__ __align__(16) u16 wl16[16 * WLS];   // conv output bf16 [oc][px]

    // ---- per-thread setup (no LDS deps) ----
    short8 bf0, bf1;
    #pragma unroll
    for (int j = 0; j < 8; ++j) {
        int k0 = kg * 8 + j;
        int k1 = 32 + kg * 8 + j;
        float v0 = (rsel < 15 && k0 < 54) ? cw[rsel * 54 + k0] : 0.f;
        float v1 = (rsel < 15 && k1 < 54) ? cw[rsel * 54 + k1] : 0.f;
        bf0[j] = (short)f2bf(v0);
        bf1[j] = (short)f2bf(v1);
    }
    const float bias = cb[rsel < 15 ? rsel : 14];
    int offA[16];
    #pragma unroll
    for (int q = 0; q < 16; ++q) {
        int k = (q >> 3) * 32 + kg * 8 + (q & 7);
        int ci = k / 9, tap = k - ci * 9, dy = tap / 3, dx = tap - dy * 3;
        offA[q] = (k < 54) ? (ci * XPL + dy * XS2 + dx) : 0;
    }

    unsigned int* xz = (unsigned int*)xpad;
    // ---- border-only zero (dword rows 0/21 + col22-23; u16 col 1) + wl K-pad ----
    #pragma unroll
    for (int i2 = 0; i2 < 2; ++i2) {
        int i = tid + i2 * 256;
        if (i < 264) {
            int pl = i / 44, d = i - pl * 44;
            int dw;
            if (d < 12) dw = d;                      // row 0
            else if (d < 24) dw = 252 + (d - 12);    // row 21
            else dw = (d - 23) * 12 + 11;            // cols 22-23, rows 1..20
            xz[pl * XPLD + dw] = 0u;
        }
    }
    if (tid < 120) {
        int pl = tid / 20, r = tid % 20 + 1;
        xpad[pl * XPL + r * 24 + 1] = 0;             // col 1, rows 1..20
    }
    if (tid < 180) {
        int row = tid / 12, d = tid % 12;
        ((unsigned int*)wl16)[row * 212 + 200 + d] = 0u;  // wl K-pad (u16 400..423)
    }

    // ---- vectorized interior fill (disjoint from border -> no barrier needed) ----
    const unsigned int* s0d = (const unsigned int*)(xdb + (size_t)b * 1200);
    const float2* s1d = (const float2*)(xres + (size_t)b * 1200);
    #pragma unroll
    for (int i2 = 0; i2 < 3; ++i2) {
        int i = tid + i2 * 256;
        if (i < 600) {
            int c = i / 200, rem = i - c * 200;
            int p = rem * 2, y = p / 20, x = p - (p / 20) * 20;   // x even
            xz[c * XPLD + (y + 1) * 12 + (x + 2) / 2] = s0d[i];
        }
    }
    #pragma unroll
    for (int i2 = 0; i2 < 3; ++i2) {
        int i = tid + i2 * 256;
        if (i < 600) {
            int c = i / 200, rem = i - c * 200;
            int p = rem * 2, y = p / 20, x = p - (p / 20) * 20;
            float2 v = s1d[i];
            unsigned int pk;
            asm volatile("v_cvt_pk_bf16_f32 %0, %1, %2" : "=v"(pk) : "v"(v.x), "v"(v.y));
            xz[(3 + c) * XPLD + (y + 1) * 12 + (x + 2) / 2] = pk;
        }
    }
    __syncthreads();   // barrier 1: xpad ready

    // ---- conv via MFMA: wave wv handles tiles t = wv, wv+4, ... < 25 ----
    for (int t = wv; t < 25; t += 4) {
        const int px = t * 16 + rsel;
        const int y = px / 20;
        const int pb = y * XS2 + (px - y * 20) + 1;   // window top-left (col = x+1)
        short8 a0, a1;
        #pragma unroll
        for (int j = 0; j < 8; ++j) a0[j] = (short)xpad[pb + offA[j]];
        #pragma unroll
        for (int j = 0; j < 8; ++j) a1[j] = (short)xpad[pb + offA[8 + j]];
        floatx4 acc = (floatx4){bias, bias, bias, bias};
        acc = __builtin_amdgcn_mfma_f32_16x16x32_bf16(a0, bf0, acc, 0, 0, 0);
        acc = __builtin_amdgcn_mfma_f32_16x16x32_bf16(a1, bf1, acc, 0, 0, 0);
        if (rsel < 15) {
            unsigned int lo, hi;
            asm volatile("v_cvt_pk_bf16_f32 %0, %1, %2" : "=v"(lo) : "v"(acc[0]), "v"(acc[1]));
            asm volatile("v_cvt_pk_bf16_f32 %0, %1, %2" : "=v"(hi) : "v"(acc[2]), "v"(acc[3]));
            *(uint2*)(wl16 + rsel * WLS + t * 16 + kg * 4) = make_uint2(lo, hi);
        }
    }
    __syncthreads();   // barrier 2: wl ready (xpad now dead -> reuse as Gsh)

    // ---- channel-Gram via MFMA, PER WAVE (no wave idles, no trailing barrier) ----
    float* Gw = ((float*)xpad) + wv * 272;   // 16x17 floats per wave
    {
        floatx4 gacc = (floatx4){0.f, 0.f, 0.f, 0.f};
        #pragma unroll
        for (int s = 0; s < 13; ++s) {
            short8 f = *(const short8*)(wl16 + rsel * WLS + s * 32 + kg * 8);
            gacc = __builtin_amdgcn_mfma_f32_16x16x32_bf16(f, f, gacc, 0, 0, 0);
        }
        #pragma unroll
        for (int r = 0; r < 4; ++r)
            Gw[(kg * 4 + r) * 17 + rsel] = gacc[r];
    }
    // same-wave lgkm ordering guarantees visibility of Gw writes to these reads.
    // Gd is SYMMETRIC: read only e >= d (45 broadcast reads), mirror the rest.
    float Gd[5][5];
    #pragma unroll
    for (int d = 0; d < 5; ++d)
        #pragma unroll
        for (int e = d; e < 5; ++e)
            Gd[d][e] = Gw[(3 * d) * 17 + 3 * e] +
                       Gw[(3 * d + 1) * 17 + 3 * e + 1] +
                       Gw[(3 * d + 2) * 17 + 3 * e + 2];
    #pragma unroll
    for (int d = 1; d < 5; ++d)
        #pragma unroll
        for (int e = 0; e < d; ++e)
            Gd[d][e] = Gd[e][d];

    // ---- per-thread Gram-space modified GS solve ----
    float A[5][5];
    #pragma unroll
    for (int i = 0; i < 5; ++i)
        #pragma unroll
        for (int j = 0; j < 5; ++j) A[i][j] = (i == j) ? 1.f : 0.f;
    #pragma unroll
    for (int j = 0; j < 4; ++j) {
        float v[5];
        #pragma unroll
        for (int rr = 0; rr < 5; ++rr) {
            float s0a = 0.f;
            #pragma unroll
            for (int k = 0; k < 5; ++k)
                if (k <= j) s0a = fmaf(A[j][k], Gd[k][rr], s0a);
            v[rr] = s0a;
        }
        float dj = 0.f;
        #pragma unroll
        for (int k = 0; k < 5; ++k)
            if (k <= j) dj = fmaf(A[j][k], v[k], dj);
        float rd = 1.0f / dj;
        #pragma unroll
        for (int i = j + 1; i < 5; ++i) {
            float cij = 0.f;
            #pragma unroll
            for (int k = 0; k < 5; ++k)
                if (k <= i) cij = fmaf(A[i][k], v[k], cij);
            cij *= rd;
            #pragma unroll
            for (int k = 0; k < 5; ++k)
                if (k <= j) A[i][k] = fmaf(-cij, A[j][k], A[i][k]);
        }
    }
    float a10[10];
    a10[0] = A[1][0];
    a10[1] = A[2][0]; a10[2] = A[2][1];
    a10[3] = A[3][0]; a10[4] = A[3][1]; a10[5] = A[3][2];
    a10[6] = A[4][0]; a10[7] = A[4][1]; a10[8] = A[4][2]; a10[9] = A[4][3];

    // ---- combine + store: 256 + 144 positions, coalesced scalar stores ----
    float* ob = out + (size_t)b * 6000;
    #pragma unroll
    for (int pp = 0; pp < 2; ++pp) {
        if (pp == 0 || tid < 144) {
            const int pos = tid + pp * 256;
            #pragma unroll
            for (int cc = 0; cc < 3; ++cc) {
                float w0 = bf2f(wl16[(0 + cc) * WLS + pos]);
                float w1 = bf2f(wl16[(3 + cc) * WLS + pos]);
                float w2v = bf2f(wl16[(6 + cc) * WLS + pos]);
                float w3 = bf2f(wl16[(9 + cc) * WLS + pos]);
                float w4 = bf2f(wl16[(12 + cc) * WLS + pos]);
                float u4 = fmaf(a10[9], w3, fmaf(a10[8], w2v, fmaf(a10[7], w1, fmaf(a10[6], w0, w4))));
                float u3 = fmaf(a10[5], w2v, fmaf(a10[4], w1, fmaf(a10[3], w0, w3)));
                float u2 = fmaf(a10[2], w1, fmaf(a10[1], w0, w2v));
                float u1 = fmaf(a10[0], w0, w1);
                ob[(0 + cc) * 400 + pos] = w0;
                ob[(3 + cc) * 400 + pos] = u1;
                ob[(6 + cc) * 400 + pos] = u2;
                ob[(9 + cc) * 400 + pos] = u3;
                ob[(12 + cc) * 400 + pos] = u4;
            }
        }
    }
}

extern "C" void kernel_launch(void* const* d_in, const int* in_sizes, int n_in,
                              void* d_out, int out_size, void* d_ws, size_t ws_size,
                              hipStream_t stream) {
    const float* x_restored  = (const float*)d_in[0];
    const float* x_distorted = (const float*)d_in[1];
    const float* w1          = (const float*)d_in[2];
    const float* w2          = (const float*)d_in[3];
    const float* b2          = (const float*)d_in[4];
    const float* conv_w      = (const float*)d_in[5];
    const float* conv_b      = (const float*)d_in[6];
    float* out = (float*)d_out;

    u16* xdb = (u16*)d_ws;                           // 8192*1200 bf16 = 19.7 MB
    u16* hb  = xdb + (size_t)NB * 1200;              // 8192*128 bf16 = 2 MB
    u16* w2b = hb + (size_t)NB * 128;                // 1200*128 bf16 = 0.3 MB

    mlp1_kernel<<<(NB * 128) / 256, 256, 0, stream>>>(x_distorted, w1, hb);
    castw2_kernel<<<(1200 * 128) / 256, 256, 0, stream>>>(w2, w2b);
    mlp2_mfma<<<(128 * 25) / 4, 256, 0, stream>>>(hb, w2b, b2, xdb);
    conv_gs_kernel<<<NB, 256, 0, stream>>>(xdb, x_restored, conv_w, conv_b, out);
}

// Round 22
// 89.293 us; speedup vs baseline: 1.1674x; 1.0557x over previous
//
#include <hip/hip_runtime.h>

// x_restored: (8192, 3, 20, 20) f32
// x_distorted: (8192, 5) f32
// w1: (128, 5), w2: (1200, 128), b2: (1200,)
// conv_w: (15, 6, 3, 3), conv_b: (15,)
// out: (8192, 5, 3, 20, 20) f32

#define NB 8192

typedef __attribute__((ext_vector_type(8))) short short8;
typedef __attribute__((ext_vector_type(4))) float floatx4;
typedef unsigned short u16;

__device__ inline u16 f2bf(float f) {
    unsigned int u = __float_as_uint(f);
    unsigned int r = (u + 0x7FFFu + ((u >> 16) & 1u)) >> 16;
    return (u16)r;
}
__device__ inline float bf2f(u16 u) {
    return __uint_as_float(((unsigned int)u) << 16);
}

// ---------------- Kernel A: h = relu(x_distorted @ w1.T) -> bf16, (B,128) ----------------
__global__ __launch_bounds__(256) void mlp1_kernel(const float* __restrict__ xdist,
                                                   const float* __restrict__ w1,
                                                   u16* __restrict__ hb) {
    int gid = blockIdx.x * 256 + threadIdx.x;
    int b = gid >> 7, j = gid & 127;
    const float* xr = xdist + b * 5;
    const float* wr = w1 + j * 5;
    float s = xr[0] * wr[0];
    s = fmaf(xr[1], wr[1], s);
    s = fmaf(xr[2], wr[2], s);
    s = fmaf(xr[3], wr[3], s);
    s = fmaf(xr[4], wr[4], s);
    hb[gid] = f2bf(fmaxf(s, 0.0f));
}

// ---------------- cast w2 -> bf16 ----------------
__global__ __launch_bounds__(256) void castw2_kernel(const float* __restrict__ w2,
                                                     u16* __restrict__ w2b) {
    int i = blockIdx.x * 256 + threadIdx.x;   // 1200*128 = 153600 exactly
    w2b[i] = f2bf(w2[i]);
}

// ---------------- Kernel B: xd = h @ w2.T + b2 via bf16 MFMA; OUTPUT IN BF16 ----------------
__global__ __launch_bounds__(256) void mlp2_mfma(const u16* __restrict__ hb,
                                                 const u16* __restrict__ w2b,
                                                 const float* __restrict__ b2,
                                                 u16* __restrict__ xdb) {
    const int tid = threadIdx.x;
    const int lane = tid & 63, wv = tid >> 6;
    const int tile = blockIdx.x * 4 + wv;          // 0..3199
    const int mt = tile / 25, nt = tile - mt * 25;
    const int rsel = lane & 15, kg = lane >> 4;

    short8 a[4][4], bfr[3][4];
    #pragma unroll
    for (int mi = 0; mi < 4; ++mi) {
        const u16* ap = hb + (size_t)(mt * 64 + mi * 16 + rsel) * 128 + kg * 8;
        #pragma unroll
        for (int ks = 0; ks < 4; ++ks) a[mi][ks] = *(const short8*)(ap + ks * 32);
    }
    #pragma unroll
    for (int ni = 0; ni < 3; ++ni) {
        const u16* bp = w2b + (size_t)(nt * 48 + ni * 16 + rsel) * 128 + kg * 8;
        #pragma unroll
        for (int ks = 0; ks < 4; ++ks) bfr[ni][ks] = *(const short8*)(bp + ks * 32);
    }
    floatx4 acc[4][3];
    #pragma unroll
    for (int mi = 0; mi < 4; ++mi)
        #pragma unroll
        for (int ni = 0; ni < 3; ++ni)
            acc[mi][ni] = (floatx4){0.f, 0.f, 0.f, 0.f};

    #pragma unroll
    for (int ks = 0; ks < 4; ++ks)
        #pragma unroll
        for (int mi = 0; mi < 4; ++mi)
            #pragma unroll
            for (int ni = 0; ni < 3; ++ni)
                acc[mi][ni] = __builtin_amdgcn_mfma_f32_16x16x32_bf16(
                    a[mi][ks], bfr[ni][ks], acc[mi][ni], 0, 0, 0);

    #pragma unroll
    for (int ni = 0; ni < 3; ++ni) {
        float bias = b2[nt * 48 + ni * 16 + rsel];
        #pragma unroll
        for (int mi = 0; mi < 4; ++mi) {
            #pragma unroll
            for (int r = 0; r < 4; ++r) {
                int m = mt * 64 + mi * 16 + kg * 4 + r;
                xdb[(size_t)m * 1200 + nt * 48 + ni * 16 + rsel] = f2bf(acc[mi][ni][r] + bias);
            }
        }
    }
}

#define XS2 24            // xpad row stride (u16, EVEN: left pad 2 -> dword-aligned fill)
#define XPL 528           // xpad plane stride (u16) = 22*24
#define XPLD 264          // xpad plane stride (dwords)
#define WLS 424           // wl row stride (u16); K padded to 416 for gram MFMA

// ---------------- Kernel C: conv via MFMA + per-wave gram-MFMA + GS, 256 thr/sample -----
// EXACT R18 kernel (measured best: 92.2 us) + global-load prefetch: the fill's 10 global
// loads are issued into registers at kernel entry, hiding HBM/L2 latency under the
// B-frag/offA/border-zero setup instead of stalling at the first LDS write.
__global__ __launch_bounds__(256) void conv_gs_kernel(const u16* __restrict__ xdb,
                                                      const float* __restrict__ xres,
                                                      const float* __restrict__ cw,
                                                      const float* __restrict__ cb,
                                                      float* __restrict__ out) {
    const int b = blockIdx.x;
    const int tid = threadIdx.x;  // 0..255
    const int lane = tid & 63, wv = tid >> 6;
    const int rsel = lane & 15, kg = lane >> 4;
    __shared__ __align__(16) u16 xpad[6 * XPL];    // 3168 u16; aliased as Gsh after conv
    __shared__ __align__(16) u16 wl16[16 * WLS];   // conv output bf16 [oc][px]

    // ---- PREFETCH: issue all fill global loads first (latency hides under setup) ----
    const unsigned int* s0d = (const unsigned int*)(xdb + (size_t)b * 1200);
    const float2* s1d = (const float2*)(xres + (size_t)b * 1200);
    unsigned int pv0[3];
    float2 pv1[3];
    pv0[0] = s0d[tid];
    pv0[1] = s0d[tid + 256];
    if (tid < 88) pv0[2] = s0d[tid + 512];
    pv1[0] = s1d[tid];
    pv1[1] = s1d[tid + 256];
    if (tid < 88) pv1[2] = s1d[tid + 512];

    // ---- per-thread setup (no LDS deps; overlaps load latency) ----
    short8 bf0, bf1;
    #pragma unroll
    for (int j = 0; j < 8; ++j) {
        int k0 = kg * 8 + j;
        int k1 = 32 + kg * 8 + j;
        float v0 = (rsel < 15 && k0 < 54) ? cw[rsel * 54 + k0] : 0.f;
        float v1 = (rsel < 15 && k1 < 54) ? cw[rsel * 54 + k1] : 0.f;
        bf0[j] = (short)f2bf(v0);
        bf1[j] = (short)f2bf(v1);
    }
    const float bias = cb[rsel < 15 ? rsel : 14];
    int offA[16];
    #pragma unroll
    for (int q = 0; q < 16; ++q) {
        int k = (q >> 3) * 32 + kg * 8 + (q & 7);
        int ci = k / 9, tap = k - ci * 9, dy = tap / 3, dx = tap - dy * 3;
        offA[q] = (k < 54) ? (ci * XPL + dy * XS2 + dx) : 0;
    }

    unsigned int* xz = (unsigned int*)xpad;
    // ---- border-only zero (dword rows 0/21 + col22-23; u16 col 1) + wl K-pad ----
    #pragma unroll
    for (int i2 = 0; i2 < 2; ++i2) {
        int i = tid + i2 * 256;
        if (i < 264) {
            int pl = i / 44, d = i - pl * 44;
            int dw;
            if (d < 12) dw = d;                      // row 0
            else if (d < 24) dw = 252 + (d - 12);    // row 21
            else dw = (d - 23) * 12 + 11;            // cols 22-23, rows 1..20
            xz[pl * XPLD + dw] = 0u;
        }
    }
    if (tid < 120) {
        int pl = tid / 20, r = tid % 20 + 1;
        xpad[pl * XPL + r * 24 + 1] = 0;             // col 1, rows 1..20
    }
    if (tid < 180) {
        int row = tid / 12, d = tid % 12;
        ((unsigned int*)wl16)[row * 212 + 200 + d] = 0u;  // wl K-pad (u16 400..423)
    }

    // ---- interior fill from prefetched registers ----
    #pragma unroll
    for (int i2 = 0; i2 < 3; ++i2) {
        int i = tid + i2 * 256;
        if (i2 < 2 || tid < 88) {
            int c = i / 200, rem = i - c * 200;
            int p = rem * 2, y = p / 20, x = p - (p / 20) * 20;   // x even
            xz[c * XPLD + (y + 1) * 12 + (x + 2) / 2] = pv0[i2];
        }
    }
    #pragma unroll
    for (int i2 = 0; i2 < 3; ++i2) {
        int i = tid + i2 * 256;
        if (i2 < 2 || tid < 88) {
            int c = i / 200, rem = i - c * 200;
            int p = rem * 2, y = p / 20, x = p - (p / 20) * 20;
            float2 v = pv1[i2];
            unsigned int pk;
            asm volatile("v_cvt_pk_bf16_f32 %0, %1, %2" : "=v"(pk) : "v"(v.x), "v"(v.y));
            xz[(3 + c) * XPLD + (y + 1) * 12 + (x + 2) / 2] = pk;
        }
    }
    __syncthreads();   // barrier 1: xpad ready

    // ---- conv via MFMA: wave wv handles tiles t = wv, wv+4, ... < 25 ----
    for (int t = wv; t < 25; t += 4) {
        const int px = t * 16 + rsel;
        const int y = px / 20;
        const int pb = y * XS2 + (px - y * 20) + 1;   // window top-left (col = x+1)
        short8 a0, a1;
        #pragma unroll
        for (int j = 0; j < 8; ++j) a0[j] = (short)xpad[pb + offA[j]];
        #pragma unroll
        for (int j = 0; j < 8; ++j) a1[j] = (short)xpad[pb + offA[8 + j]];
        floatx4 acc = (floatx4){bias, bias, bias, bias};
        acc = __builtin_amdgcn_mfma_f32_16x16x32_bf16(a0, bf0, acc, 0, 0, 0);
        acc = __builtin_amdgcn_mfma_f32_16x16x32_bf16(a1, bf1, acc, 0, 0, 0);
        if (rsel < 15) {
            unsigned int lo, hi;
            asm volatile("v_cvt_pk_bf16_f32 %0, %1, %2" : "=v"(lo) : "v"(acc[0]), "v"(acc[1]));
            asm volatile("v_cvt_pk_bf16_f32 %0, %1, %2" : "=v"(hi) : "v"(acc[2]), "v"(acc[3]));
            *(uint2*)(wl16 + rsel * WLS + t * 16 + kg * 4) = make_uint2(lo, hi);
        }
    }
    __syncthreads();   // barrier 2: wl ready (xpad now dead -> reuse as Gsh)

    // ---- channel-Gram via MFMA, PER WAVE (no wave idles, no trailing barrier) ----
    float* Gw = ((float*)xpad) + wv * 272;   // 16x17 floats per wave
    {
        floatx4 gacc = (floatx4){0.f, 0.f, 0.f, 0.f};
        #pragma unroll
        for (int s = 0; s < 13; ++s) {
            short8 f = *(const short8*)(wl16 + rsel * WLS + s * 32 + kg * 8);
            gacc = __builtin_amdgcn_mfma_f32_16x16x32_bf16(f, f, gacc, 0, 0, 0);
        }
        #pragma unroll
        for (int r = 0; r < 4; ++r)
            Gw[(kg * 4 + r) * 17 + rsel] = gacc[r];
    }
    // same-wave lgkm ordering guarantees visibility of Gw writes to these reads
    float Gd[5][5];
    #pragma unroll
    for (int d = 0; d < 5; ++d)
        #pragma unroll
        for (int e = 0; e < 5; ++e)
            Gd[d][e] = Gw[(3 * d) * 17 + 3 * e] +
                       Gw[(3 * d + 1) * 17 + 3 * e + 1] +
                       Gw[(3 * d + 2) * 17 + 3 * e + 2];

    // ---- per-thread Gram-space modified GS solve ----
    float A[5][5];
    #pragma unroll
    for (int i = 0; i < 5; ++i)
        #pragma unroll
        for (int j = 0; j < 5; ++j) A[i][j] = (i == j) ? 1.f : 0.f;
    #pragma unroll
    for (int j = 0; j < 4; ++j) {
        float v[5];
        #pragma unroll
        for (int rr = 0; rr < 5; ++rr) {
            float s0a = 0.f;
            #pragma unroll
            for (int k = 0; k < 5; ++k)
                if (k <= j) s0a = fmaf(A[j][k], Gd[k][rr], s0a);
            v[rr] = s0a;
        }
        float dj = 0.f;
        #pragma unroll
        for (int k = 0; k < 5; ++k)
            if (k <= j) dj = fmaf(A[j][k], v[k], dj);
        float rd = 1.0f / dj;
        #pragma unroll
        for (int i = j + 1; i < 5; ++i) {
            float cij = 0.f;
            #pragma unroll
            for (int k = 0; k < 5; ++k)
                if (k <= i) cij = fmaf(A[i][k], v[k], cij);
            cij *= rd;
            #pragma unroll
            for (int k = 0; k < 5; ++k)
                if (k <= j) A[i][k] = fmaf(-cij, A[j][k], A[i][k]);
        }
    }
    float a10[10];
    a10[0] = A[1][0];
    a10[1] = A[2][0]; a10[2] = A[2][1];
    a10[3] = A[3][0]; a10[4] = A[3][1]; a10[5] = A[3][2];
    a10[6] = A[4][0]; a10[7] = A[4][1]; a10[8] = A[4][2]; a10[9] = A[4][3];

    // ---- combine + store: 256 + 144 positions, coalesced scalar stores ----
    float* ob = out + (size_t)b * 6000;
    #pragma unroll
    for (int pp = 0; pp < 2; ++pp) {
        if (pp == 0 || tid < 144) {
            const int pos = tid + pp * 256;
            #pragma unroll
            for (int cc = 0; cc < 3; ++cc) {
                float w0 = bf2f(wl16[(0 + cc) * WLS + pos]);
                float w1 = bf2f(wl16[(3 + cc) * WLS + pos]);
                float w2v = bf2f(wl16[(6 + cc) * WLS + pos]);
                float w3 = bf2f(wl16[(9 + cc) * WLS + pos]);
                float w4 = bf2f(wl16[(12 + cc) * WLS + pos]);
                float u4 = fmaf(a10[9], w3, fmaf(a10[8], w2v, fmaf(a10[7], w1, fmaf(a10[6], w0, w4))));
                float u3 = fmaf(a10[5], w2v, fmaf(a10[4], w1, fmaf(a10[3], w0, w3)));
                float u2 = fmaf(a10[2], w1, fmaf(a10[1], w0, w2v));
                float u1 = fmaf(a10[0], w0, w1);
                ob[(0 + cc) * 400 + pos] = w0;
                ob[(3 + cc) * 400 + pos] = u1;
                ob[(6 + cc) * 400 + pos] = u2;
                ob[(9 + cc) * 400 + pos] = u3;
                ob[(12 + cc) * 400 + pos] = u4;
            }
        }
    }
}

extern "C" void kernel_launch(void* const* d_in, const int* in_sizes, int n_in,
                              void* d_out, int out_size, void* d_ws, size_t ws_size,
                              hipStream_t stream) {
    const float* x_restored  = (const float*)d_in[0];
    const float* x_distorted = (const float*)d_in[1];
    const float* w1          = (const float*)d_in[2];
    const float* w2          = (const float*)d_in[3];
    const float* b2          = (const float*)d_in[4];
    const float* conv_w      = (const float*)d_in[5];
    const float* conv_b      = (const float*)d_in[6];
    float* out = (float*)d_out;

    u16* xdb = (u16*)d_ws;                           // 8192*1200 bf16 = 19.7 MB
    u16* hb  = xdb + (size_t)NB * 1200;              // 8192*128 bf16 = 2 MB
    u16* w2b = hb + (size_t)NB * 128;                // 1200*128 bf16 = 0.3 MB

    mlp1_kernel<<<(NB * 128) / 256, 256, 0, stream>>>(x_distorted, w1, hb);
    castw2_kernel<<<(1200 * 128) / 256, 256, 0, stream>>>(w2, w2b);
    mlp2_mfma<<<(128 * 25) / 4, 256, 0, stream>>>(hb, w2b, b2, xdb);
    conv_gs_kernel<<<NB, 256, 0, stream>>>(xdb, x_restored, conv_w, conv_b, out);
}